// Round 4
// baseline (323.726 us; speedup 1.0000x reference)
//
#include <hip/hip_runtime.h>
#include <hip/hip_bf16.h>
#include <stdint.h>
#include <cmath>

// IDXST_IDCT on MI355X: y = S · x · C^T with
//   C[v,q] = cos(pi*q*(2v+1)/(2N)),  S[u,p] = sin(pi*p*(2u+1)/(2M))
// Butterfly decomposition (halves GEMM FLOPs):
//   C[N-1-v,q] = (-1)^q C[v,q]  ->  t[v]=E+O,  t[N-1-v]=E-O
//   S[M-1-u,p] = -(-1)^p S[u,p] ->  y[u]=E+O,  y[M-1-u]=O-E
// R4: butterflies FUSED into the GEMM epilogues — each block runs two
// sequential K-loop phases (even/odd), keeps both acc tiles in registers,
// butterflies in fp32, and writes final outputs directly.

typedef __attribute__((ext_vector_type(4))) float f32x4;
typedef __attribute__((ext_vector_type(8))) unsigned short u16x8;
typedef __attribute__((ext_vector_type(8))) __bf16 bf16x8;

__device__ __forceinline__ unsigned short f2bf(float f) {
  union { float f; unsigned u; } v; v.f = f;
  unsigned u = v.u + 0x7fffu + ((v.u >> 16) & 1u);  // RNE
  return (unsigned short)(u >> 16);
}

// ---- fp32 -> bf16 convert + even/odd column deinterleave ----
__global__ void convert_deint_kernel(const f32x4* __restrict__ x,
                                     u16x8* __restrict__ xe,
                                     u16x8* __restrict__ xo, int n16) {
  int idx = blockIdx.x * blockDim.x + threadIdx.x;
  if (idx >= n16) return;
  f32x4 a = x[4 * idx], b = x[4 * idx + 1], c = x[4 * idx + 2],
        d = x[4 * idx + 3];
  u16x8 e, o;
  e[0] = f2bf(a[0]); o[0] = f2bf(a[1]); e[1] = f2bf(a[2]); o[1] = f2bf(a[3]);
  e[2] = f2bf(b[0]); o[2] = f2bf(b[1]); e[3] = f2bf(b[2]); o[3] = f2bf(b[3]);
  e[4] = f2bf(c[0]); o[4] = f2bf(c[1]); e[5] = f2bf(c[2]); o[5] = f2bf(c[3]);
  e[6] = f2bf(d[0]); o[6] = f2bf(d[1]); e[7] = f2bf(d[2]); o[7] = f2bf(d[3]);
  xe[idx] = e; xo[idx] = o;
}

// ---- generate half transform matrices [L/2 x L/2] bf16 ----
// Pe[i,j] = f(pi*(2j)(2i+1)/(2L)), Po[i,j] = f(pi*(2j+1)(2i+1)/(2L)).
__global__ void gen_half_kernel(u16x8* __restrict__ Pe, u16x8* __restrict__ Po,
                                int isSin, int jshift, int jmask,
                                unsigned mask4L, float sc) {
  int idx = blockIdx.x * blockDim.x + threadIdx.x;
  int i = idx >> jshift;           // row
  int jb = (idx & jmask) * 8;      // first col
  unsigned tp = 2u * (unsigned)i + 1u;
  unsigned re = (2u * (unsigned)jb * tp) & mask4L;
  unsigned ro = (re + tp) & mask4L;
  unsigned step = (2u * tp) & mask4L;
  u16x8 pe, po;
#pragma unroll
  for (int t = 0; t < 8; t++) {
    float se_, ce_, so_, co_;
    __sincosf((float)re * sc, &se_, &ce_);
    __sincosf((float)ro * sc, &so_, &co_);
    pe[t] = f2bf(isSin ? se_ : ce_);
    po[t] = f2bf(isSin ? so_ : co_);
    re = (re + step) & mask4L;
    ro = (ro + step) & mask4L;
  }
  Pe[idx] = pe;
  Po[idx] = po;
}

// ---- fused bt-GEMM pair + butterfly epilogue ----
// Phase E: accE[m,n] = sum_k Ae[m,k]*Be[n,k]; Phase O with Ao/Bo.
// STAGE==1: m=v (rows of tT), n=p; write tTe/tTo (bf16, p-parity deint):
//   (p&1?tTo:tTe)[v, p>>1]        = E+O
//   (p&1?tTo:tTe)[Nfull-1-v, p>>1]= E-O
// STAGE==2: m=u, n=v; write y (fp32):
//   y[u,v] = E+O;  y[Mfull-1-u,v] = O-E
template <int STAGE>
__global__ __launch_bounds__(256, 2) void btgemm_bfly_kernel(
    const unsigned short* __restrict__ Ae,
    const unsigned short* __restrict__ Ao,
    const unsigned short* __restrict__ Be,
    const unsigned short* __restrict__ Bo,
    void* __restrict__ out0, void* __restrict__ out1,
    int outStride, int K, int Lfull) {
  __shared__ unsigned short As[128 * 32];
  __shared__ unsigned short Bs[128 * 32];

  const int tid = threadIdx.x;
  const int m0 = blockIdx.y * 128;
  const int n0 = blockIdx.x * 128;

  const int wave = tid >> 6;
  const int lane = tid & 63;
  const int wm = (wave & 1) * 64;
  const int wn = (wave >> 1) * 64;
  const int l16 = lane & 15;
  const int quad = lane >> 4;

  const int rs0 = wave * 16 + (lane >> 2);
  const int rs1 = 64 + rs0;
  const int cs = (lane & 3) * 8;
  unsigned short* Al0 = As + wave * 512;
  unsigned short* Al1 = As + 2048 + wave * 512;
  unsigned short* Bl0 = Bs + wave * 512;
  unsigned short* Bl1 = Bs + 2048 + wave * 512;

  f32x4 accE[4][4], accO[4][4];

  auto kloop = [&](const unsigned short* __restrict__ A,
                   const unsigned short* __restrict__ Bt,
                   f32x4 (&acc)[4][4]) {
#pragma unroll
    for (int i = 0; i < 4; i++)
#pragma unroll
      for (int j = 0; j < 4; j++) acc[i][j] = f32x4{0.f, 0.f, 0.f, 0.f};

    const unsigned short* Ag0 = A + (size_t)(m0 + rs0) * K + cs;
    const unsigned short* Ag1 = A + (size_t)(m0 + rs1) * K + cs;
    const unsigned short* Bg0 = Bt + (size_t)(n0 + rs0) * K + cs;
    const unsigned short* Bg1 = Bt + (size_t)(n0 + rs1) * K + cs;

    for (int k0 = 0; k0 < K; k0 += 32) {
      __builtin_amdgcn_global_load_lds(
          (const __attribute__((address_space(1))) void*)(Ag0 + k0),
          (__attribute__((address_space(3))) void*)Al0, 16, 0, 0);
      __builtin_amdgcn_global_load_lds(
          (const __attribute__((address_space(1))) void*)(Ag1 + k0),
          (__attribute__((address_space(3))) void*)Al1, 16, 0, 0);
      __builtin_amdgcn_global_load_lds(
          (const __attribute__((address_space(1))) void*)(Bg0 + k0),
          (__attribute__((address_space(3))) void*)Bl0, 16, 0, 0);
      __builtin_amdgcn_global_load_lds(
          (const __attribute__((address_space(1))) void*)(Bg1 + k0),
          (__attribute__((address_space(3))) void*)Bl1, 16, 0, 0);
      __syncthreads();

      bf16x8 af[4], bfr[4];
#pragma unroll
      for (int i = 0; i < 4; i++) {
        af[i]  = *(const bf16x8*)(As + (wm + i * 16 + l16) * 32 + quad * 8);
        bfr[i] = *(const bf16x8*)(Bs + (wn + i * 16 + l16) * 32 + quad * 8);
      }
#pragma unroll
      for (int i = 0; i < 4; i++)
#pragma unroll
        for (int j = 0; j < 4; j++)
          acc[i][j] = __builtin_amdgcn_mfma_f32_16x16x32_bf16(
              af[i], bfr[j], acc[i][j], 0, 0, 0);
      __syncthreads();
    }
  };

  kloop(Ae, Be, accE);
  kloop(Ao, Bo, accO);

  // epilogue: D row = quad*4 + reg, col = lane&15
#pragma unroll
  for (int i = 0; i < 4; i++) {
#pragma unroll
    for (int j = 0; j < 4; j++) {
      int n = n0 + wn + j * 16 + l16;
      int mb = m0 + wm + i * 16 + quad * 4;
#pragma unroll
      for (int r = 0; r < 4; r++) {
        float e = accE[i][j][r];
        float o = accO[i][j][r];
        int m = mb + r;
        if (STAGE == 1) {
          unsigned short* mat =
              (n & 1) ? (unsigned short*)out1 : (unsigned short*)out0;
          int col = n >> 1;
          mat[(size_t)m * outStride + col] = f2bf(e + o);
          mat[(size_t)(Lfull - 1 - m) * outStride + col] = f2bf(e - o);
        } else {
          float* y = (float*)out0;
          y[(size_t)m * outStride + n] = e + o;
          y[(size_t)(Lfull - 1 - m) * outStride + n] = o - e;
        }
      }
    }
  }
}

extern "C" void kernel_launch(void* const* d_in, const int* in_sizes, int n_in,
                              void* d_out, int out_size, void* d_ws,
                              size_t ws_size, hipStream_t stream) {
  const float* x = (const float*)d_in[0];
  const int M = in_sizes[1] / 2;  // expkM is [M,2]
  const int N = in_sizes[2] / 2;  // expkN is [N,2]
  const size_t MN = (size_t)M * N;

  // workspace (u16 units), 2.5*MN u16 = 80 MB @4096:
  //  [0, MN/2)        xe   [M x N/2]
  //  [MN/2, MN)       xo   [M x N/2]
  //  [MN, MN*5/4)     Ae   (Ce then Se)
  //  [MN*5/4, MN*3/2) Ao   (Co then So)
  //  [MN*3/2, MN*2)   tTe  [N x M/2]
  //  [MN*2, MN*5/2)   tTo  [N x M/2]
  unsigned short* ws = (unsigned short*)d_ws;
  unsigned short* xe = ws;
  unsigned short* xo = ws + MN / 2;
  unsigned short* Ae = ws + MN;
  unsigned short* Ao = ws + MN + MN / 4;
  unsigned short* tTe = ws + MN * 3 / 2;
  unsigned short* tTo = ws + MN * 2;

  int shiftN = 0; while ((1 << shiftN) < N) shiftN++;
  int shiftM = 0; while ((1 << shiftM) < M) shiftM++;

  // 1: convert + deinterleave x columns by parity
  int n16 = (int)(MN / 16);
  convert_deint_kernel<<<(n16 + 255) / 256, 256, 0, stream>>>(
      (const f32x4*)x, (u16x8*)xe, (u16x8*)xo, n16);

  // 2: Ce, Co (cos, modulus 4N)
  {
    int threads = (N / 2) * (N / 2) / 8;
    gen_half_kernel<<<threads / 256, 256, 0, stream>>>(
        (u16x8*)Ae, (u16x8*)Ao, 0, shiftN - 4, (N / 16) - 1,
        (unsigned)(4 * N - 1), (float)(3.14159265358979323846 / (2.0 * N)));
  }

  // 3: stage 1 fused: tT[v]=E+O, tT[N-1-v]=E-O, p-parity deint -> tTe/tTo
  btgemm_bfly_kernel<1><<<dim3(M / 128, (N / 2) / 128), 256, 0, stream>>>(
      Ae, Ao, xe, xo, tTe, tTo, M / 2, N / 2, N);

  // 4: Se, So (sin, modulus 4M) over Ae/Ao
  {
    int threads = (M / 2) * (M / 2) / 8;
    gen_half_kernel<<<threads / 256, 256, 0, stream>>>(
        (u16x8*)Ae, (u16x8*)Ao, 1, shiftM - 4, (M / 16) - 1,
        (unsigned)(4 * M - 1), (float)(3.14159265358979323846 / (2.0 * M)));
  }

  // 5: stage 2 fused: y[u]=E+O, y[M-1-u]=O-E
  btgemm_bfly_kernel<2><<<dim3(N / 128, (M / 2) / 128), 256, 0, stream>>>(
      Ae, Ao, tTe, tTo, d_out, nullptr, N, M / 2, M);
}

// Round 5
// 320.092 us; speedup vs baseline: 1.0114x; 1.0114x over previous
//
#include <hip/hip_runtime.h>
#include <hip/hip_bf16.h>
#include <stdint.h>
#include <cmath>

// IDXST_IDCT on MI355X: y = S · x · C^T with
//   C[v,q] = cos(pi*q*(2v+1)/(2N)),  S[u,p] = sin(pi*p*(2u+1)/(2M))
// Butterfly decomposition (halves GEMM FLOPs):
//   C[N-1-v,q] = (-1)^q C[v,q]  ->  t[v]=E+O,  t[N-1-v]=E-O
//   S[M-1-u,p] = -(-1)^p S[u,p] ->  y[u]=E+O,  y[M-1-u]=O-E
// R5: unfused GEMMs (R4 showed fusion loses 2x occupancy to dual-acc and the
// GEMM is LDS-read-bound); all prep (convert/deint + both trig gens) merged
// into ONE dispatch. 5 dispatches total.

typedef __attribute__((ext_vector_type(4))) float f32x4;
typedef __attribute__((ext_vector_type(8))) unsigned short u16x8;
typedef __attribute__((ext_vector_type(8))) __bf16 bf16x8;

__device__ __forceinline__ unsigned short f2bf(float f) {
  union { float f; unsigned u; } v; v.f = f;
  unsigned u = v.u + 0x7fffu + ((v.u >> 16) & 1u);  // RNE
  return (unsigned short)(u >> 16);
}
__device__ __forceinline__ float bf2f(unsigned short h) {
  union { unsigned u; float f; } v; v.u = ((unsigned)h) << 16;
  return v.f;
}

// ---- gen device helper: half transform matrices [L/2 x L/2] bf16 ----
// Pe[i,j] = f(pi*(2j)(2i+1)/(2L)), Po[i,j] = f(pi*(2j+1)(2i+1)/(2L)).
// r tracked mod 4L (power of two -> exact in u32).
__device__ __forceinline__ void gen_half(int idx, u16x8* Pe, u16x8* Po,
                                         int isSin, int jshift, int jmask,
                                         unsigned mask4L, float sc) {
  int i = idx >> jshift;           // row
  int jb = (idx & jmask) * 8;      // first col
  unsigned tp = 2u * (unsigned)i + 1u;
  unsigned re = (2u * (unsigned)jb * tp) & mask4L;
  unsigned ro = (re + tp) & mask4L;
  unsigned step = (2u * tp) & mask4L;
  u16x8 pe, po;
#pragma unroll
  for (int t = 0; t < 8; t++) {
    float se_, ce_, so_, co_;
    __sincosf((float)re * sc, &se_, &ce_);
    __sincosf((float)ro * sc, &so_, &co_);
    pe[t] = f2bf(isSin ? se_ : ce_);
    po[t] = f2bf(isSin ? so_ : co_);
    re = (re + step) & mask4L;
    ro = (ro + step) & mask4L;
  }
  Pe[idx] = pe;
  Po[idx] = po;
}

// ---- single prep dispatch: convert+deint | gen Ce/Co | gen Se/So ----
__global__ void prep_kernel(const f32x4* __restrict__ x, u16x8* __restrict__ xe,
                            u16x8* __restrict__ xo, u16x8* __restrict__ Ce,
                            u16x8* __restrict__ Co, u16x8* __restrict__ Se,
                            u16x8* __restrict__ So, int nConvBlocks,
                            int nGenNBlocks, int jshiftN, int jmaskN,
                            unsigned mask4N, float scN, int jshiftM, int jmaskM,
                            unsigned mask4M, float scM) {
  int b = blockIdx.x;
  if (b < nConvBlocks) {
    // fp32 -> bf16 + even/odd column deinterleave, 16 floats/thread
    int idx = b * 256 + threadIdx.x;
    f32x4 a = x[4 * idx], bb = x[4 * idx + 1], c = x[4 * idx + 2],
          d = x[4 * idx + 3];
    u16x8 e, o;
    e[0] = f2bf(a[0]);  o[0] = f2bf(a[1]);  e[1] = f2bf(a[2]);  o[1] = f2bf(a[3]);
    e[2] = f2bf(bb[0]); o[2] = f2bf(bb[1]); e[3] = f2bf(bb[2]); o[3] = f2bf(bb[3]);
    e[4] = f2bf(c[0]);  o[4] = f2bf(c[1]);  e[5] = f2bf(c[2]);  o[5] = f2bf(c[3]);
    e[6] = f2bf(d[0]);  o[6] = f2bf(d[1]);  e[7] = f2bf(d[2]);  o[7] = f2bf(d[3]);
    xe[idx] = e;
    xo[idx] = o;
  } else if (b < nConvBlocks + nGenNBlocks) {
    int idx = (b - nConvBlocks) * 256 + threadIdx.x;
    gen_half(idx, Ce, Co, 0, jshiftN, jmaskN, mask4N, scN);
  } else {
    int idx = (b - nConvBlocks - nGenNBlocks) * 256 + threadIdx.x;
    gen_half(idx, Se, So, 1, jshiftM, jmaskM, mask4M, scM);
  }
}

// ---- bt-GEMM: C[m,n] = sum_k A[m,k] * Bt[n,k], bf16 in, fp32 acc ----
// BM=BN=128, BK=32, 256 threads (4 waves). blockIdx.z selects (A,B,C) set.
// Staging via global_load_lds width=16 (wave-uniform base + lane*16).
template <bool OUT_BF16>
__global__ __launch_bounds__(256, 2) void btgemm_kernel(
    const unsigned short* __restrict__ A0,
    const unsigned short* __restrict__ A1,
    const unsigned short* __restrict__ B0,
    const unsigned short* __restrict__ B1,
    void* __restrict__ C0v, void* __restrict__ C1v, int Ndim, int K) {
  __shared__ unsigned short As[128 * 32];
  __shared__ unsigned short Bs[128 * 32];

  const unsigned short* A = blockIdx.z ? A1 : A0;
  const unsigned short* Bt = blockIdx.z ? B1 : B0;
  void* C = blockIdx.z ? C1v : C0v;

  const int tid = threadIdx.x;
  const int m0 = blockIdx.y * 128;
  const int n0 = blockIdx.x * 128;

  const int wave = tid >> 6;
  const int lane = tid & 63;
  const int wm = (wave & 1) * 64;
  const int wn = (wave >> 1) * 64;
  const int l16 = lane & 15;
  const int quad = lane >> 4;

  f32x4 acc[4][4];
#pragma unroll
  for (int i = 0; i < 4; i++)
#pragma unroll
    for (int j = 0; j < 4; j++) acc[i][j] = f32x4{0.f, 0.f, 0.f, 0.f};

  const int rs0 = wave * 16 + (lane >> 2);
  const int rs1 = 64 + rs0;
  const int cs = (lane & 3) * 8;
  const unsigned short* Ag0 = A + (size_t)(m0 + rs0) * K + cs;
  const unsigned short* Ag1 = A + (size_t)(m0 + rs1) * K + cs;
  const unsigned short* Bg0 = Bt + (size_t)(n0 + rs0) * K + cs;
  const unsigned short* Bg1 = Bt + (size_t)(n0 + rs1) * K + cs;
  unsigned short* Al0 = As + wave * 512;
  unsigned short* Al1 = As + 2048 + wave * 512;
  unsigned short* Bl0 = Bs + wave * 512;
  unsigned short* Bl1 = Bs + 2048 + wave * 512;

  for (int k0 = 0; k0 < K; k0 += 32) {
    __builtin_amdgcn_global_load_lds(
        (const __attribute__((address_space(1))) void*)(Ag0 + k0),
        (__attribute__((address_space(3))) void*)Al0, 16, 0, 0);
    __builtin_amdgcn_global_load_lds(
        (const __attribute__((address_space(1))) void*)(Ag1 + k0),
        (__attribute__((address_space(3))) void*)Al1, 16, 0, 0);
    __builtin_amdgcn_global_load_lds(
        (const __attribute__((address_space(1))) void*)(Bg0 + k0),
        (__attribute__((address_space(3))) void*)Bl0, 16, 0, 0);
    __builtin_amdgcn_global_load_lds(
        (const __attribute__((address_space(1))) void*)(Bg1 + k0),
        (__attribute__((address_space(3))) void*)Bl1, 16, 0, 0);
    __syncthreads();

    bf16x8 af[4], bfr[4];
#pragma unroll
    for (int i = 0; i < 4; i++) {
      af[i]  = *(const bf16x8*)(As + (wm + i * 16 + l16) * 32 + quad * 8);
      bfr[i] = *(const bf16x8*)(Bs + (wn + i * 16 + l16) * 32 + quad * 8);
    }
#pragma unroll
    for (int i = 0; i < 4; i++)
#pragma unroll
      for (int j = 0; j < 4; j++)
        acc[i][j] = __builtin_amdgcn_mfma_f32_16x16x32_bf16(af[i], bfr[j],
                                                            acc[i][j], 0, 0, 0);
    __syncthreads();
  }

  // epilogue: D row = quad*4 + reg, col = lane&15
#pragma unroll
  for (int i = 0; i < 4; i++) {
#pragma unroll
    for (int j = 0; j < 4; j++) {
      int col = n0 + wn + j * 16 + l16;
      int rowb = m0 + wm + i * 16 + quad * 4;
#pragma unroll
      for (int r = 0; r < 4; r++) {
        float v = acc[i][j][r];
        if (OUT_BF16)
          ((unsigned short*)C)[(size_t)(rowb + r) * Ndim + col] = f2bf(v);
        else
          ((float*)C)[(size_t)(rowb + r) * Ndim + col] = v;
      }
    }
  }
}

// ---- butterfly 1: E1,O1 [N/2 x M] bf16 -> tTe,tTo [N x M/2] bf16 ----
// t[v,p]=E+O, t[N-1-v,p]=E-O; simultaneously deinterleave by p parity.
__global__ void bfly1_kernel(const u16x8* __restrict__ E1,
                             const u16x8* __restrict__ O1,
                             u16x8* __restrict__ tTe, u16x8* __restrict__ tTo,
                             int pshift, int pmask, int Nrows, int Mh8) {
  int idx = blockIdx.x * blockDim.x + threadIdx.x;
  int v = idx >> pshift;            // row of E1 (0..N/2)
  int pu = idx & pmask;             // p-chunk within row (16 cols each)
  u16x8 e0 = E1[2 * idx], e1 = E1[2 * idx + 1];
  u16x8 o0 = O1[2 * idx], o1 = O1[2 * idx + 1];
  u16x8 tet, tot, teb, tob;
#pragma unroll
  for (int k = 0; k < 4; k++) {
    float ee = bf2f(e0[2 * k]), eo = bf2f(e0[2 * k + 1]);
    float oe = bf2f(o0[2 * k]), oo = bf2f(o0[2 * k + 1]);
    tet[k] = f2bf(ee + oe); tot[k] = f2bf(eo + oo);
    teb[k] = f2bf(ee - oe); tob[k] = f2bf(eo - oo);
  }
#pragma unroll
  for (int k = 0; k < 4; k++) {
    float ee = bf2f(e1[2 * k]), eo = bf2f(e1[2 * k + 1]);
    float oe = bf2f(o1[2 * k]), oo = bf2f(o1[2 * k + 1]);
    tet[4 + k] = f2bf(ee + oe); tot[4 + k] = f2bf(eo + oo);
    teb[4 + k] = f2bf(ee - oe); tob[4 + k] = f2bf(eo - oo);
  }
  tTe[idx] = tet;
  tTo[idx] = tot;
  int idxb = (Nrows - 1 - v) * Mh8 + pu;
  tTe[idxb] = teb;
  tTo[idxb] = tob;
}

// ---- butterfly 2: E2,O2 [M/2 x N] fp32 -> y [M x N] fp32 ----
// y[u]=E2+O2, y[M-1-u]=O2-E2. 16 floats per thread.
__global__ void bfly2_kernel(const f32x4* __restrict__ E2,
                             const f32x4* __restrict__ O2,
                             f32x4* __restrict__ y, int vshift, int vmask,
                             int Mrows, int N4) {
  int idx = blockIdx.x * blockDim.x + threadIdx.x;
  int u = idx >> vshift;
  int vu = (idx & vmask) * 4;       // f32x4 units within row
  int baseb = (Mrows - 1 - u) * N4 + vu;
  int baset = u * N4 + vu;
#pragma unroll
  for (int t = 0; t < 4; t++) {
    f32x4 e = E2[4 * idx + t];
    f32x4 o = O2[4 * idx + t];
    y[baset + t] = e + o;
    y[baseb + t] = o - e;
  }
}

extern "C" void kernel_launch(void* const* d_in, const int* in_sizes, int n_in,
                              void* d_out, int out_size, void* d_ws,
                              size_t ws_size, hipStream_t stream) {
  const float* x = (const float*)d_in[0];
  const int M = in_sizes[1] / 2;  // expkM is [M,2]
  const int N = in_sizes[2] / 2;  // expkN is [N,2]
  const size_t MN = (size_t)M * N;

  // workspace (u16 units), 4*MN u16 = 128 MB @4096:
  //  [0, MN/2)          xe   [M x N/2]        (later E2 fp32 [M/2 x N] spans [0,MN))
  //  [MN/2, MN)         xo   [M x N/2]
  //  [MN, 3MN/2)        tTe  [N x M/2]
  //  [3MN/2, 2MN)       tTo  [N x M/2]
  //  [2MN, 9MN/4)       Ce   [N/2 x N/2]
  //  [9MN/4, 5MN/2)     Co
  //  [5MN/2, 11MN/4)    Se   [M/2 x M/2]
  //  [11MN/4, 3MN)      So
  //  [3MN, 7MN/2)       E1   [N/2 x M]        (later O2 fp32 spans [3MN,4MN))
  //  [7MN/2, 4MN)       O1   [N/2 x M]
  unsigned short* ws = (unsigned short*)d_ws;
  unsigned short* xe = ws;
  unsigned short* xo = ws + MN / 2;
  unsigned short* tTe = ws + MN;
  unsigned short* tTo = ws + MN * 3 / 2;
  unsigned short* Ce = ws + MN * 2;
  unsigned short* Co = ws + MN * 2 + MN / 4;
  unsigned short* Se = ws + MN * 5 / 2;
  unsigned short* So = ws + MN * 5 / 2 + MN / 4;
  unsigned short* E1 = ws + MN * 3;
  unsigned short* O1 = ws + MN * 7 / 2;
  float* E2 = (float*)ws;               // over dead xe/xo
  float* O2 = (float*)(ws + MN * 3);    // over dead E1/O1

  int shiftN = 0; while ((1 << shiftN) < N) shiftN++;
  int shiftM = 0; while ((1 << shiftM) < M) shiftM++;

  // 1: fused prep — convert+deint, gen Ce/Co, gen Se/So
  int nConvBlocks = (int)(MN / 16 / 256);
  int nGenNBlocks = (N / 2) * (N / 2) / 8 / 256;
  int nGenMBlocks = (M / 2) * (M / 2) / 8 / 256;
  prep_kernel<<<nConvBlocks + nGenNBlocks + nGenMBlocks, 256, 0, stream>>>(
      (const f32x4*)x, (u16x8*)xe, (u16x8*)xo, (u16x8*)Ce, (u16x8*)Co,
      (u16x8*)Se, (u16x8*)So, nConvBlocks, nGenNBlocks, shiftN - 4,
      (N / 16) - 1, (unsigned)(4 * N - 1),
      (float)(3.14159265358979323846 / (2.0 * N)), shiftM - 4, (M / 16) - 1,
      (unsigned)(4 * M - 1), (float)(3.14159265358979323846 / (2.0 * M)));

  // 2: stage-1 half GEMMs: E1 = Ce·xe^T, O1 = Co·xo^T (out bf16, stride M)
  btgemm_kernel<true><<<dim3(M / 128, (N / 2) / 128, 2), 256, 0, stream>>>(
      Ce, Co, xe, xo, E1, O1, M, N / 2);

  // 3: butterfly + p-parity deinterleave -> tTe, tTo
  bfly1_kernel<<<(int)(MN / 32 / 256), 256, 0, stream>>>(
      (const u16x8*)E1, (const u16x8*)O1, (u16x8*)tTe, (u16x8*)tTo, shiftM - 4,
      (M / 16) - 1, N, M / 16);

  // 4: stage-2 half GEMMs: E2 = Se·tTe^T, O2 = So·tTo^T (out fp32, stride N)
  btgemm_kernel<false><<<dim3(N / 128, (M / 2) / 128, 2), 256, 0, stream>>>(
      Se, So, tTe, tTo, E2, O2, N, M / 2);

  // 5: final butterfly -> y
  bfly2_kernel<<<(int)(MN / 32 / 256), 256, 0, stream>>>(
      (const f32x4*)E2, (const f32x4*)O2, (f32x4*)d_out, shiftN - 4,
      (N / 16) - 1, M, N / 4);
}

// Round 6
// 282.337 us; speedup vs baseline: 1.1466x; 1.1337x over previous
//
#include <hip/hip_runtime.h>
#include <hip/hip_bf16.h>
#include <stdint.h>
#include <cmath>

// IDXST_IDCT on MI355X: y = S · x · C^T with
//   C[v,q] = cos(pi*q*(2v+1)/(2N)),  S[u,p] = sin(pi*p*(2u+1)/(2M))
// Level-1 butterfly halves GEMM FLOPs:
//   C[N-1-v,q] = (-1)^q C[v,q]  ->  t[v]=E+O,  t[N-1-v]=E-O
//   S[M-1-u,p] = -(-1)^p S[u,p] ->  y[u]=E+O,  y[M-1-u]=O-E
// R6: BK=64 K-loop (half the barrier drains) with XOR-swizzled LDS layout
// (kcol8 ^ row&7) to keep ds_read_b128 bank-balanced; stage-2 outputs bf16
// (halves E2/O2 round-trip traffic).

typedef __attribute__((ext_vector_type(4))) float f32x4;
typedef __attribute__((ext_vector_type(8))) unsigned short u16x8;
typedef __attribute__((ext_vector_type(8))) __bf16 bf16x8;

__device__ __forceinline__ unsigned short f2bf(float f) {
  union { float f; unsigned u; } v; v.f = f;
  unsigned u = v.u + 0x7fffu + ((v.u >> 16) & 1u);  // RNE
  return (unsigned short)(u >> 16);
}
__device__ __forceinline__ float bf2f(unsigned short h) {
  union { unsigned u; float f; } v; v.u = ((unsigned)h) << 16;
  return v.f;
}

// ---- gen device helper: half transform matrices [L/2 x L/2] bf16 ----
// Pe[i,j] = f(pi*(2j)(2i+1)/(2L)), Po[i,j] = f(pi*(2j+1)(2i+1)/(2L)).
// r tracked mod 4L (power of two -> exact in u32).
__device__ __forceinline__ void gen_half(int idx, u16x8* Pe, u16x8* Po,
                                         int isSin, int jshift, int jmask,
                                         unsigned mask4L, float sc) {
  int i = idx >> jshift;           // row
  int jb = (idx & jmask) * 8;      // first col
  unsigned tp = 2u * (unsigned)i + 1u;
  unsigned re = (2u * (unsigned)jb * tp) & mask4L;
  unsigned ro = (re + tp) & mask4L;
  unsigned step = (2u * tp) & mask4L;
  u16x8 pe, po;
#pragma unroll
  for (int t = 0; t < 8; t++) {
    float se_, ce_, so_, co_;
    __sincosf((float)re * sc, &se_, &ce_);
    __sincosf((float)ro * sc, &so_, &co_);
    pe[t] = f2bf(isSin ? se_ : ce_);
    po[t] = f2bf(isSin ? so_ : co_);
    re = (re + step) & mask4L;
    ro = (ro + step) & mask4L;
  }
  Pe[idx] = pe;
  Po[idx] = po;
}

// ---- single prep dispatch: convert+deint | gen Ce/Co | gen Se/So ----
__global__ void prep_kernel(const f32x4* __restrict__ x, u16x8* __restrict__ xe,
                            u16x8* __restrict__ xo, u16x8* __restrict__ Ce,
                            u16x8* __restrict__ Co, u16x8* __restrict__ Se,
                            u16x8* __restrict__ So, int nConvBlocks,
                            int nGenNBlocks, int jshiftN, int jmaskN,
                            unsigned mask4N, float scN, int jshiftM, int jmaskM,
                            unsigned mask4M, float scM) {
  int b = blockIdx.x;
  if (b < nConvBlocks) {
    int idx = b * 256 + threadIdx.x;
    f32x4 a = x[4 * idx], bb = x[4 * idx + 1], c = x[4 * idx + 2],
          d = x[4 * idx + 3];
    u16x8 e, o;
    e[0] = f2bf(a[0]);  o[0] = f2bf(a[1]);  e[1] = f2bf(a[2]);  o[1] = f2bf(a[3]);
    e[2] = f2bf(bb[0]); o[2] = f2bf(bb[1]); e[3] = f2bf(bb[2]); o[3] = f2bf(bb[3]);
    e[4] = f2bf(c[0]);  o[4] = f2bf(c[1]);  e[5] = f2bf(c[2]);  o[5] = f2bf(c[3]);
    e[6] = f2bf(d[0]);  o[6] = f2bf(d[1]);  e[7] = f2bf(d[2]);  o[7] = f2bf(d[3]);
    xe[idx] = e;
    xo[idx] = o;
  } else if (b < nConvBlocks + nGenNBlocks) {
    int idx = (b - nConvBlocks) * 256 + threadIdx.x;
    gen_half(idx, Ce, Co, 0, jshiftN, jmaskN, mask4N, scN);
  } else {
    int idx = (b - nConvBlocks - nGenNBlocks) * 256 + threadIdx.x;
    gen_half(idx, Se, So, 1, jshiftM, jmaskM, mask4M, scM);
  }
}

// ---- bt-GEMM: C[m,n] = sum_k A[m,k] * Bt[n,k], bf16 in/out, fp32 acc ----
// BM=BN=128, BK=64, 256 threads (4 waves, 2x2). blockIdx.z picks (A,B,C).
// LDS tiles 128x64 with XOR swizzle: element (row, col) lives at
// row*64 + ((col/8) ^ (row&7))*8 + col%8. Staging (global_load_lds, 16B/lane,
// 1KB chunk = 8 rows): lane l sources global col ((l&7)^(l>>3))*8 so the
// swizzled LDS slot receives the right data; dst stays uniform+lane*16.
__global__ __launch_bounds__(256, 2) void btgemm_kernel(
    const unsigned short* __restrict__ A0,
    const unsigned short* __restrict__ A1,
    const unsigned short* __restrict__ B0,
    const unsigned short* __restrict__ B1,
    unsigned short* __restrict__ C0, unsigned short* __restrict__ C1, int Ndim,
    int K) {
  __shared__ unsigned short As[128 * 64];
  __shared__ unsigned short Bs[128 * 64];

  const unsigned short* A = blockIdx.z ? A1 : A0;
  const unsigned short* Bt = blockIdx.z ? B1 : B0;
  unsigned short* C = blockIdx.z ? C1 : C0;

  const int tid = threadIdx.x;
  const int m0 = blockIdx.y * 128;
  const int n0 = blockIdx.x * 128;

  const int wave = tid >> 6;
  const int lane = tid & 63;
  const int wm = (wave & 1) * 64;
  const int wn = (wave >> 1) * 64;
  const int l16 = lane & 15;
  const int quad = lane >> 4;

  f32x4 acc[4][4];
#pragma unroll
  for (int i = 0; i < 4; i++)
#pragma unroll
    for (int j = 0; j < 4; j++) acc[i][j] = f32x4{0.f, 0.f, 0.f, 0.f};

  // staging addresses: chunk ch = wave + 4t covers rows [8ch, 8ch+8)
  const int lrow = lane >> 3;                 // row within chunk
  const int lsw = ((lane & 7) ^ lrow) * 8;    // swizzled source col (elems)
  const unsigned short* Ag[4];
  const unsigned short* Bg[4];
  unsigned short* Al[4];
  unsigned short* Bl[4];
#pragma unroll
  for (int t = 0; t < 4; t++) {
    int ch = wave + 4 * t;
    Ag[t] = A + (size_t)(m0 + 8 * ch + lrow) * K + lsw;
    Bg[t] = Bt + (size_t)(n0 + 8 * ch + lrow) * K + lsw;
    Al[t] = As + ch * 512;
    Bl[t] = Bs + ch * 512;
  }

  const int swz = (quad ^ (l16 & 7)) * 8;     // k-half 0 frag col (elems)

  for (int k0 = 0; k0 < K; k0 += 64) {
#pragma unroll
    for (int t = 0; t < 4; t++) {
      __builtin_amdgcn_global_load_lds(
          (const __attribute__((address_space(1))) void*)(Ag[t] + k0),
          (__attribute__((address_space(3))) void*)Al[t], 16, 0, 0);
      __builtin_amdgcn_global_load_lds(
          (const __attribute__((address_space(1))) void*)(Bg[t] + k0),
          (__attribute__((address_space(3))) void*)Bl[t], 16, 0, 0);
    }
    __syncthreads();

#pragma unroll
    for (int h = 0; h < 2; h++) {
      const int so = swz ^ (h * 32);
      bf16x8 af[4], bfr[4];
#pragma unroll
      for (int i = 0; i < 4; i++) {
        af[i]  = *(const bf16x8*)(As + (wm + i * 16 + l16) * 64 + so);
        bfr[i] = *(const bf16x8*)(Bs + (wn + i * 16 + l16) * 64 + so);
      }
#pragma unroll
      for (int i = 0; i < 4; i++)
#pragma unroll
        for (int j = 0; j < 4; j++)
          acc[i][j] = __builtin_amdgcn_mfma_f32_16x16x32_bf16(
              af[i], bfr[j], acc[i][j], 0, 0, 0);
    }
    __syncthreads();
  }

  // epilogue: D row = quad*4 + reg, col = lane&15
#pragma unroll
  for (int i = 0; i < 4; i++) {
#pragma unroll
    for (int j = 0; j < 4; j++) {
      int col = n0 + wn + j * 16 + l16;
      int rowb = m0 + wm + i * 16 + quad * 4;
#pragma unroll
      for (int r = 0; r < 4; r++)
        C[(size_t)(rowb + r) * Ndim + col] = f2bf(acc[i][j][r]);
    }
  }
}

// ---- butterfly 1: E1,O1 [N/2 x M] bf16 -> tTe,tTo [N x M/2] bf16 ----
// t[v,p]=E+O, t[N-1-v,p]=E-O; simultaneously deinterleave by p parity.
__global__ void bfly1_kernel(const u16x8* __restrict__ E1,
                             const u16x8* __restrict__ O1,
                             u16x8* __restrict__ tTe, u16x8* __restrict__ tTo,
                             int pshift, int pmask, int Nrows, int Mh8) {
  int idx = blockIdx.x * blockDim.x + threadIdx.x;
  int v = idx >> pshift;
  int pu = idx & pmask;
  u16x8 e0 = E1[2 * idx], e1 = E1[2 * idx + 1];
  u16x8 o0 = O1[2 * idx], o1 = O1[2 * idx + 1];
  u16x8 tet, tot, teb, tob;
#pragma unroll
  for (int k = 0; k < 4; k++) {
    float ee = bf2f(e0[2 * k]), eo = bf2f(e0[2 * k + 1]);
    float oe = bf2f(o0[2 * k]), oo = bf2f(o0[2 * k + 1]);
    tet[k] = f2bf(ee + oe); tot[k] = f2bf(eo + oo);
    teb[k] = f2bf(ee - oe); tob[k] = f2bf(eo - oo);
  }
#pragma unroll
  for (int k = 0; k < 4; k++) {
    float ee = bf2f(e1[2 * k]), eo = bf2f(e1[2 * k + 1]);
    float oe = bf2f(o1[2 * k]), oo = bf2f(o1[2 * k + 1]);
    tet[4 + k] = f2bf(ee + oe); tot[4 + k] = f2bf(eo + oo);
    teb[4 + k] = f2bf(ee - oe); tob[4 + k] = f2bf(eo - oo);
  }
  tTe[idx] = tet;
  tTo[idx] = tot;
  int idxb = (Nrows - 1 - v) * Mh8 + pu;
  tTe[idxb] = teb;
  tTo[idxb] = tob;
}

// ---- butterfly 2: E2,O2 [M/2 x N] bf16 -> y [M x N] fp32 ----
// y[u]=E+O, y[M-1-u]=O-E. 16 elems per thread.
__global__ void bfly2_kernel(const u16x8* __restrict__ E2,
                             const u16x8* __restrict__ O2,
                             f32x4* __restrict__ y, int vshift, int vmask,
                             int Mrows, int N4) {
  int idx = blockIdx.x * blockDim.x + threadIdx.x;
  int u = idx >> vshift;
  int vu = (idx & vmask) * 4;
  u16x8 e0 = E2[2 * idx], e1 = E2[2 * idx + 1];
  u16x8 o0 = O2[2 * idx], o1 = O2[2 * idx + 1];
  int baset = u * N4 + vu;
  int baseb = (Mrows - 1 - u) * N4 + vu;
#pragma unroll
  for (int t = 0; t < 2; t++) {
    f32x4 tv, bv;
#pragma unroll
    for (int k = 0; k < 4; k++) {
      float e = bf2f(e0[t * 4 + k]);
      float o = bf2f(o0[t * 4 + k]);
      tv[k] = e + o;
      bv[k] = o - e;
    }
    y[baset + t] = tv;
    y[baseb + t] = bv;
  }
#pragma unroll
  for (int t = 0; t < 2; t++) {
    f32x4 tv, bv;
#pragma unroll
    for (int k = 0; k < 4; k++) {
      float e = bf2f(e1[t * 4 + k]);
      float o = bf2f(o1[t * 4 + k]);
      tv[k] = e + o;
      bv[k] = o - e;
    }
    y[baset + 2 + t] = tv;
    y[baseb + 2 + t] = bv;
  }
}

extern "C" void kernel_launch(void* const* d_in, const int* in_sizes, int n_in,
                              void* d_out, int out_size, void* d_ws,
                              size_t ws_size, hipStream_t stream) {
  const float* x = (const float*)d_in[0];
  const int M = in_sizes[1] / 2;  // expkM is [M,2]
  const int N = in_sizes[2] / 2;  // expkN is [N,2]
  const size_t MN = (size_t)M * N;

  // workspace (u16 units), 4*MN u16 = 128 MB @4096:
  //  [0, MN/2)        xe  [M x N/2]   (later E2 bf16 [M/2 x N])
  //  [MN/2, MN)       xo  [M x N/2]   (later O2 bf16)
  //  [MN, 5MN/4)      Ce ; [5MN/4, 3MN/2) Co
  //  [3MN/2, 7MN/4)   Se ; [7MN/4, 2MN)   So
  //  [2MN, 5MN/2)     E1  [N/2 x M]
  //  [5MN/2, 3MN)     O1  [N/2 x M]
  //  [3MN, 7MN/2)     tTe [N x M/2]
  //  [7MN/2, 4MN)     tTo [N x M/2]
  unsigned short* ws = (unsigned short*)d_ws;
  unsigned short* xe = ws;
  unsigned short* xo = ws + MN / 2;
  unsigned short* Ce = ws + MN;
  unsigned short* Co = ws + MN + MN / 4;
  unsigned short* Se = ws + MN * 3 / 2;
  unsigned short* So = ws + MN * 7 / 4;
  unsigned short* E1 = ws + MN * 2;
  unsigned short* O1 = ws + MN * 5 / 2;
  unsigned short* tTe = ws + MN * 3;
  unsigned short* tTo = ws + MN * 7 / 2;
  unsigned short* E2 = xe;  // overlay: xe/xo dead after stage-1 GEMM
  unsigned short* O2 = xo;

  int shiftN = 0; while ((1 << shiftN) < N) shiftN++;
  int shiftM = 0; while ((1 << shiftM) < M) shiftM++;

  // 1: fused prep — convert+deint, gen Ce/Co, gen Se/So
  int nConvBlocks = (int)(MN / 16 / 256);
  int nGenNBlocks = (N / 2) * (N / 2) / 8 / 256;
  int nGenMBlocks = (M / 2) * (M / 2) / 8 / 256;
  prep_kernel<<<nConvBlocks + nGenNBlocks + nGenMBlocks, 256, 0, stream>>>(
      (const f32x4*)x, (u16x8*)xe, (u16x8*)xo, (u16x8*)Ce, (u16x8*)Co,
      (u16x8*)Se, (u16x8*)So, nConvBlocks, nGenNBlocks, shiftN - 4,
      (N / 16) - 1, (unsigned)(4 * N - 1),
      (float)(3.14159265358979323846 / (2.0 * N)), shiftM - 4, (M / 16) - 1,
      (unsigned)(4 * M - 1), (float)(3.14159265358979323846 / (2.0 * M)));

  // 2: stage-1 half GEMMs: E1 = Ce·xe^T, O1 = Co·xo^T (bf16, stride M)
  btgemm_kernel<<<dim3(M / 128, (N / 2) / 128, 2), 256, 0, stream>>>(
      Ce, Co, xe, xo, E1, O1, M, N / 2);

  // 3: butterfly + p-parity deinterleave -> tTe, tTo
  bfly1_kernel<<<(int)(MN / 32 / 256), 256, 0, stream>>>(
      (const u16x8*)E1, (const u16x8*)O1, (u16x8*)tTe, (u16x8*)tTo, shiftM - 4,
      (M / 16) - 1, N, M / 16);

  // 4: stage-2 half GEMMs: E2 = Se·tTe^T, O2 = So·tTo^T (bf16, stride N)
  btgemm_kernel<<<dim3(N / 128, (M / 2) / 128, 2), 256, 0, stream>>>(
      Se, So, tTe, tTo, E2, O2, N, M / 2);

  // 5: final butterfly -> y (fp32)
  bfly2_kernel<<<(int)(MN / 32 / 256), 256, 0, stream>>>(
      (const u16x8*)E2, (const u16x8*)O2, (f32x4*)d_out, shiftN - 4,
      (N / 16) - 1, M, N / 4);
}

// Round 7
// 272.836 us; speedup vs baseline: 1.1865x; 1.0348x over previous
//
#include <hip/hip_runtime.h>
#include <hip/hip_bf16.h>
#include <stdint.h>
#include <cmath>

// IDXST_IDCT on MI355X: y = S · x · C^T with
//   C[v,q] = cos(pi*q*(2v+1)/(2N)),  S[u,p] = sin(pi*p*(2u+1)/(2M))
// Butterfly halves GEMM FLOPs:
//   C[N-1-v,q] = (-1)^q C[v,q]  ->  t[v]=E+O,  t[N-1-v]=E-O
//   S[M-1-u,p] = -(-1)^p S[u,p] ->  y[u]=E+O,  y[M-1-u]=O-E
// R7: butterflies fused into GEMM epilogues via dual fp32 accumulators.
// Works now (unlike R4) because BK=64 makes the fused grid (512 blocks)
// exactly 2 blocks/CU — grid-limited occupancy, so dual-acc VGPRs are free.
// K-loop: BK=64, XOR-swizzled LDS (zero bank conflicts), global_load_lds x16.
// 3 dispatches total: prep, F1 (GEMM+bfly1+deint), F2 (GEMM+bfly2).

typedef __attribute__((ext_vector_type(4))) float f32x4;
typedef __attribute__((ext_vector_type(8))) unsigned short u16x8;
typedef __attribute__((ext_vector_type(8))) __bf16 bf16x8;

__device__ __forceinline__ unsigned short f2bf(float f) {
  union { float f; unsigned u; } v; v.f = f;
  unsigned u = v.u + 0x7fffu + ((v.u >> 16) & 1u);  // RNE
  return (unsigned short)(u >> 16);
}

// ---- gen device helper: half transform matrices [L/2 x L/2] bf16 ----
// Pe[i,j] = f(pi*(2j)(2i+1)/(2L)), Po[i,j] = f(pi*(2j+1)(2i+1)/(2L)).
// r tracked mod 4L (power of two -> exact in u32).
__device__ __forceinline__ void gen_half(int idx, u16x8* Pe, u16x8* Po,
                                         int isSin, int jshift, int jmask,
                                         unsigned mask4L, float sc) {
  int i = idx >> jshift;           // row
  int jb = (idx & jmask) * 8;      // first col
  unsigned tp = 2u * (unsigned)i + 1u;
  unsigned re = (2u * (unsigned)jb * tp) & mask4L;
  unsigned ro = (re + tp) & mask4L;
  unsigned step = (2u * tp) & mask4L;
  u16x8 pe, po;
#pragma unroll
  for (int t = 0; t < 8; t++) {
    float se_, ce_, so_, co_;
    __sincosf((float)re * sc, &se_, &ce_);
    __sincosf((float)ro * sc, &so_, &co_);
    pe[t] = f2bf(isSin ? se_ : ce_);
    po[t] = f2bf(isSin ? so_ : co_);
    re = (re + step) & mask4L;
    ro = (ro + step) & mask4L;
  }
  Pe[idx] = pe;
  Po[idx] = po;
}

// ---- single prep dispatch: convert+deint | gen Ce/Co | gen Se/So ----
__global__ void prep_kernel(const f32x4* __restrict__ x, u16x8* __restrict__ xe,
                            u16x8* __restrict__ xo, u16x8* __restrict__ Ce,
                            u16x8* __restrict__ Co, u16x8* __restrict__ Se,
                            u16x8* __restrict__ So, int nConvBlocks,
                            int nGenNBlocks, int jshiftN, int jmaskN,
                            unsigned mask4N, float scN, int jshiftM, int jmaskM,
                            unsigned mask4M, float scM) {
  int b = blockIdx.x;
  if (b < nConvBlocks) {
    int idx = b * 256 + threadIdx.x;
    f32x4 a = x[4 * idx], bb = x[4 * idx + 1], c = x[4 * idx + 2],
          d = x[4 * idx + 3];
    u16x8 e, o;
    e[0] = f2bf(a[0]);  o[0] = f2bf(a[1]);  e[1] = f2bf(a[2]);  o[1] = f2bf(a[3]);
    e[2] = f2bf(bb[0]); o[2] = f2bf(bb[1]); e[3] = f2bf(bb[2]); o[3] = f2bf(bb[3]);
    e[4] = f2bf(c[0]);  o[4] = f2bf(c[1]);  e[5] = f2bf(c[2]);  o[5] = f2bf(c[3]);
    e[6] = f2bf(d[0]);  o[6] = f2bf(d[1]);  e[7] = f2bf(d[2]);  o[7] = f2bf(d[3]);
    xe[idx] = e;
    xo[idx] = o;
  } else if (b < nConvBlocks + nGenNBlocks) {
    int idx = (b - nConvBlocks) * 256 + threadIdx.x;
    gen_half(idx, Ce, Co, 0, jshiftN, jmaskN, mask4N, scN);
  } else {
    int idx = (b - nConvBlocks - nGenNBlocks) * 256 + threadIdx.x;
    gen_half(idx, Se, So, 1, jshiftM, jmaskM, mask4M, scM);
  }
}

// ---- fused dual bt-GEMM + butterfly epilogue ----
// accE[m,n] = sum_k Ae[m,k]*Be[n,k]; accO likewise with Ao/Bo (sequential
// K-loops sharing the swizzled LDS). BM=BN=128, BK=64, 256 threads (2x2
// waves of 64x64). LDS: elem (row,col) at row*64 + ((col/8)^(row&7))*8 +
// col%8; staging lane l sources global col ((l&7)^(l>>3))*8 so dst stays
// wave-uniform-base + lane*16.
// STAGE==1 (m=v, n=p): (p&1?out1:out0)[v, p>>1] = E+O;
//                      [...][Lfull-1-v, p>>1]   = E-O   (bf16)
// STAGE==2 (m=u, n=v): y[u,v] = E+O; y[Lfull-1-u,v] = O-E  (fp32, out0)
template <int STAGE>
__global__ __launch_bounds__(256, 2) void fused_gemm_kernel(
    const unsigned short* __restrict__ Ae,
    const unsigned short* __restrict__ Ao,
    const unsigned short* __restrict__ Be,
    const unsigned short* __restrict__ Bo,
    unsigned short* __restrict__ out0, unsigned short* __restrict__ out1,
    int outStride, int K, int Lfull) {
  __shared__ unsigned short As[128 * 64];
  __shared__ unsigned short Bs[128 * 64];

  const int tid = threadIdx.x;
  const int m0 = blockIdx.y * 128;
  const int n0 = blockIdx.x * 128;

  const int wave = tid >> 6;
  const int lane = tid & 63;
  const int wm = (wave & 1) * 64;
  const int wn = (wave >> 1) * 64;
  const int l16 = lane & 15;
  const int quad = lane >> 4;

  // staging: chunk ch = wave + 4t covers rows [8ch, 8ch+8)
  const int lrow = lane >> 3;                 // row within chunk
  const int lsw = ((lane & 7) ^ lrow) * 8;    // swizzled source col (elems)
  unsigned short* Al[4];
  unsigned short* Bl[4];
#pragma unroll
  for (int t = 0; t < 4; t++) {
    int ch = wave + 4 * t;
    Al[t] = As + ch * 512;
    Bl[t] = Bs + ch * 512;
  }
  const int swz = (quad ^ (l16 & 7)) * 8;     // frag col for k-half 0

  f32x4 accE[4][4], accO[4][4];

  auto kloop = [&](const unsigned short* __restrict__ A,
                   const unsigned short* __restrict__ Bt,
                   f32x4 (&acc)[4][4]) {
#pragma unroll
    for (int i = 0; i < 4; i++)
#pragma unroll
      for (int j = 0; j < 4; j++) acc[i][j] = f32x4{0.f, 0.f, 0.f, 0.f};

    const unsigned short* Ag[4];
    const unsigned short* Bg[4];
#pragma unroll
    for (int t = 0; t < 4; t++) {
      int ch = wave + 4 * t;
      Ag[t] = A + (size_t)(m0 + 8 * ch + lrow) * K + lsw;
      Bg[t] = Bt + (size_t)(n0 + 8 * ch + lrow) * K + lsw;
    }

    for (int k0 = 0; k0 < K; k0 += 64) {
#pragma unroll
      for (int t = 0; t < 4; t++) {
        __builtin_amdgcn_global_load_lds(
            (const __attribute__((address_space(1))) void*)(Ag[t] + k0),
            (__attribute__((address_space(3))) void*)Al[t], 16, 0, 0);
        __builtin_amdgcn_global_load_lds(
            (const __attribute__((address_space(1))) void*)(Bg[t] + k0),
            (__attribute__((address_space(3))) void*)Bl[t], 16, 0, 0);
      }
      __syncthreads();

#pragma unroll
      for (int h = 0; h < 2; h++) {
        const int so = swz ^ (h * 32);
        bf16x8 af[4], bfr[4];
#pragma unroll
        for (int i = 0; i < 4; i++) {
          af[i]  = *(const bf16x8*)(As + (wm + i * 16 + l16) * 64 + so);
          bfr[i] = *(const bf16x8*)(Bs + (wn + i * 16 + l16) * 64 + so);
        }
#pragma unroll
        for (int i = 0; i < 4; i++)
#pragma unroll
          for (int j = 0; j < 4; j++)
            acc[i][j] = __builtin_amdgcn_mfma_f32_16x16x32_bf16(
                af[i], bfr[j], acc[i][j], 0, 0, 0);
      }
      __syncthreads();
    }
  };

  kloop(Ae, Be, accE);
  kloop(Ao, Bo, accO);

  // epilogue: D row = quad*4 + reg, col = lane&15; butterfly E/O in fp32
#pragma unroll
  for (int i = 0; i < 4; i++) {
#pragma unroll
    for (int j = 0; j < 4; j++) {
      int n = n0 + wn + j * 16 + l16;
      int mb = m0 + wm + i * 16 + quad * 4;
#pragma unroll
      for (int r = 0; r < 4; r++) {
        float e = accE[i][j][r];
        float o = accO[i][j][r];
        int m = mb + r;
        if (STAGE == 1) {
          unsigned short* mat = (n & 1) ? out1 : out0;
          int c = n >> 1;
          mat[(size_t)m * outStride + c] = f2bf(e + o);
          mat[(size_t)(Lfull - 1 - m) * outStride + c] = f2bf(e - o);
        } else {
          float* y = (float*)out0;
          y[(size_t)m * outStride + n] = e + o;
          y[(size_t)(Lfull - 1 - m) * outStride + n] = o - e;
        }
      }
    }
  }
}

extern "C" void kernel_launch(void* const* d_in, const int* in_sizes, int n_in,
                              void* d_out, int out_size, void* d_ws,
                              size_t ws_size, hipStream_t stream) {
  const float* x = (const float*)d_in[0];
  const int M = in_sizes[1] / 2;  // expkM is [M,2]
  const int N = in_sizes[2] / 2;  // expkN is [N,2]
  const size_t MN = (size_t)M * N;

  // workspace (u16 units), 3*MN u16 = 96 MB @4096:
  //  [0, MN/2)      xe  [M x N/2]
  //  [MN/2, MN)     xo  [M x N/2]
  //  [MN, 5MN/4)    Ce ; [5MN/4, 3MN/2) Co     [N/2 x N/2]
  //  [3MN/2, 7MN/4) Se ; [7MN/4, 2MN)   So     [M/2 x M/2]
  //  [2MN, 5MN/2)   tTe [N x M/2]
  //  [5MN/2, 3MN)   tTo [N x M/2]
  unsigned short* ws = (unsigned short*)d_ws;
  unsigned short* xe = ws;
  unsigned short* xo = ws + MN / 2;
  unsigned short* Ce = ws + MN;
  unsigned short* Co = ws + MN + MN / 4;
  unsigned short* Se = ws + MN * 3 / 2;
  unsigned short* So = ws + MN * 7 / 4;
  unsigned short* tTe = ws + MN * 2;
  unsigned short* tTo = ws + MN * 5 / 2;

  int shiftN = 0; while ((1 << shiftN) < N) shiftN++;
  int shiftM = 0; while ((1 << shiftM) < M) shiftM++;

  // 1: fused prep — convert+deint, gen Ce/Co, gen Se/So
  int nConvBlocks = (int)(MN / 16 / 256);
  int nGenNBlocks = (N / 2) * (N / 2) / 8 / 256;
  int nGenMBlocks = (M / 2) * (M / 2) / 8 / 256;
  prep_kernel<<<nConvBlocks + nGenNBlocks + nGenMBlocks, 256, 0, stream>>>(
      (const f32x4*)x, (u16x8*)xe, (u16x8*)xo, (u16x8*)Ce, (u16x8*)Co,
      (u16x8*)Se, (u16x8*)So, nConvBlocks, nGenNBlocks, shiftN - 4,
      (N / 16) - 1, (unsigned)(4 * N - 1),
      (float)(3.14159265358979323846 / (2.0 * N)), shiftM - 4, (M / 16) - 1,
      (unsigned)(4 * M - 1), (float)(3.14159265358979323846 / (2.0 * M)));

  // 2: F1 — E/O GEMMs (K=N/2) + v-butterfly + p-parity deint -> tTe/tTo
  fused_gemm_kernel<1><<<dim3(M / 128, (N / 2) / 128), 256, 0, stream>>>(
      Ce, Co, xe, xo, tTe, tTo, M / 2, N / 2, N);

  // 3: F2 — E/O GEMMs (K=M/2) + u-butterfly -> y fp32
  fused_gemm_kernel<2><<<dim3(N / 128, (M / 2) / 128), 256, 0, stream>>>(
      Se, So, tTe, tTo, (unsigned short*)d_out, nullptr, N, M / 2, M);
}